// Round 3
// baseline (350.087 us; speedup 1.0000x reference)
//
#include <hip/hip_runtime.h>
#include <math.h>

#define BB 2
#define CC 64
#define HH 128
#define WW 160
#define DD 16
#define VV 4
#define NNB 9
#define GG 8
#define HWSZ (HH*WW)
#define BNS 0.99999500003749977f  // 1/sqrt(1+1e-5)

// ---------------- 4x4 inverse (adjugate) ----------------
__device__ inline void inv4(const float* m, float* o) {
    float inv[16];
    inv[0]  =  m[5]*m[10]*m[15] - m[5]*m[11]*m[14] - m[9]*m[6]*m[15] + m[9]*m[7]*m[14] + m[13]*m[6]*m[11] - m[13]*m[7]*m[10];
    inv[4]  = -m[4]*m[10]*m[15] + m[4]*m[11]*m[14] + m[8]*m[6]*m[15] - m[8]*m[7]*m[14] - m[12]*m[6]*m[11] + m[12]*m[7]*m[10];
    inv[8]  =  m[4]*m[9]*m[15]  - m[4]*m[11]*m[13] - m[8]*m[5]*m[15] + m[8]*m[7]*m[13] + m[12]*m[5]*m[11] - m[12]*m[7]*m[9];
    inv[12] = -m[4]*m[9]*m[14]  + m[4]*m[10]*m[13] + m[8]*m[5]*m[14] - m[8]*m[6]*m[13] - m[12]*m[5]*m[10] + m[12]*m[6]*m[9];
    inv[1]  = -m[1]*m[10]*m[15] + m[1]*m[11]*m[14] + m[9]*m[2]*m[15] - m[9]*m[3]*m[14] - m[13]*m[2]*m[11] + m[13]*m[3]*m[10];
    inv[5]  =  m[0]*m[10]*m[15] - m[0]*m[11]*m[14] - m[8]*m[2]*m[15] + m[8]*m[3]*m[14] + m[12]*m[2]*m[11] - m[12]*m[3]*m[10];
    inv[9]  = -m[0]*m[9]*m[15]  + m[0]*m[11]*m[13] + m[8]*m[1]*m[15] - m[8]*m[3]*m[13] - m[12]*m[1]*m[11] + m[12]*m[3]*m[9];
    inv[13] =  m[0]*m[9]*m[14]  - m[0]*m[10]*m[13] - m[8]*m[1]*m[14] + m[8]*m[2]*m[13] + m[12]*m[1]*m[10] - m[12]*m[2]*m[9];
    inv[2]  =  m[1]*m[6]*m[15]  - m[1]*m[7]*m[14]  - m[5]*m[2]*m[15] + m[5]*m[3]*m[14] + m[13]*m[2]*m[7]  - m[13]*m[3]*m[6];
    inv[6]  = -m[0]*m[6]*m[15]  + m[0]*m[7]*m[14]  + m[4]*m[2]*m[15] - m[4]*m[3]*m[14] - m[12]*m[2]*m[7]  + m[12]*m[3]*m[6];
    inv[10] =  m[0]*m[5]*m[15]  - m[0]*m[7]*m[13]  - m[4]*m[1]*m[15] + m[4]*m[3]*m[13] + m[12]*m[1]*m[7]  - m[12]*m[3]*m[5];
    inv[14] = -m[0]*m[5]*m[14]  + m[0]*m[6]*m[13]  + m[4]*m[1]*m[14] - m[4]*m[2]*m[13] - m[12]*m[1]*m[6]  + m[12]*m[2]*m[5];
    inv[3]  = -m[1]*m[6]*m[11]  + m[1]*m[7]*m[10]  + m[5]*m[2]*m[11] - m[5]*m[3]*m[10] - m[9]*m[2]*m[7]   + m[9]*m[3]*m[6];
    inv[7]  =  m[0]*m[6]*m[11]  - m[0]*m[7]*m[10]  - m[4]*m[2]*m[11] + m[4]*m[3]*m[10] + m[8]*m[2]*m[7]   - m[8]*m[3]*m[6];
    inv[11] = -m[0]*m[5]*m[11]  + m[0]*m[7]*m[9]   + m[4]*m[1]*m[11] - m[4]*m[3]*m[9]  - m[8]*m[1]*m[7]   + m[8]*m[3]*m[5];
    inv[15] =  m[0]*m[5]*m[10]  - m[0]*m[6]*m[9]   - m[4]*m[1]*m[10] + m[4]*m[2]*m[9]  + m[8]*m[1]*m[6]   - m[8]*m[2]*m[5];
    float det = m[0]*inv[0] + m[1]*inv[4] + m[2]*inv[8] + m[3]*inv[12];
    det = 1.0f/det;
    #pragma unroll
    for (int i=0;i<16;++i) o[i] = inv[i]*det;
}

// ---------------- prep: proj matrices + folded net weights ----------------
// ws layout (floats): [0..95] proj (V*B x 12), [96..384] pw net, [385..673] sn net
__global__ void prep_k(const float* __restrict__ ref_proj, const float* __restrict__ src_projs,
                       const float* __restrict__ pw_w0, const float* __restrict__ pw_g0, const float* __restrict__ pw_b0,
                       const float* __restrict__ pw_w1, const float* __restrict__ pw_g1, const float* __restrict__ pw_b1,
                       const float* __restrict__ pw_w2, const float* __restrict__ pw_c2b,
                       const float* __restrict__ sn_w0, const float* __restrict__ sn_g0, const float* __restrict__ sn_b0,
                       const float* __restrict__ sn_w1, const float* __restrict__ sn_g1, const float* __restrict__ sn_b1,
                       const float* __restrict__ sn_w2, const float* __restrict__ sn_c2b,
                       float* __restrict__ ws) {
    int t = threadIdx.x;
    if (t < VV*BB) {
        int b = t % BB;
        float Mi[16];
        inv4(ref_proj + b*16, Mi);
        const float* A = src_projs + t*16;
        float P[16];
        #pragma unroll
        for (int i=0;i<4;++i)
            #pragma unroll
            for (int j=0;j<4;++j) {
                float s = 0.f;
                #pragma unroll
                for (int k=0;k<4;++k) s += A[i*4+k]*Mi[k*4+j];
                P[i*4+j] = s;
            }
        float* o = ws + t*12;
        o[0]=P[0]; o[1]=P[1]; o[2]=P[2];
        o[3]=P[4]; o[4]=P[5]; o[5]=P[6];
        o[6]=P[8]; o[7]=P[9]; o[8]=P[10];
        o[9]=P[3]; o[10]=P[7]; o[11]=P[11];
    }
    if (t < 128) {
        ws[96 + t]        = pw_w0[t]*pw_g0[t>>3]*BNS;
        ws[96 + 144 + t]  = pw_w1[t]*pw_g1[t>>4]*BNS;
        ws[385 + t]       = sn_w0[t]*sn_g0[t>>3]*BNS;
        ws[385 + 144 + t] = sn_w1[t]*sn_g1[t>>4]*BNS;
    }
    if (t < 16) { ws[96+128+t]=pw_b0[t]; ws[385+128+t]=sn_b0[t]; }
    if (t < 8)  { ws[96+272+t]=pw_b1[t]; ws[96+280+t]=pw_w2[t];
                  ws[385+272+t]=sn_b1[t]; ws[385+280+t]=sn_w2[t]; }
    if (t == 0) { ws[96+288]=pw_c2b[0]; ws[385+288]=sn_c2b[0]; }
}

// ---------------- combined transpose [img][64][HW] -> [img][HW][64] ----------------
// blockIdx.y < BB -> ref image, else src image (blockIdx.y - BB)
__global__ __launch_bounds__(256) void transpose2_k(const float* __restrict__ ref,
                                                    const float* __restrict__ src,
                                                    float* __restrict__ ref_t,
                                                    float* __restrict__ src_t) {
    __shared__ float tb[64][65];
    int img = blockIdx.y;
    const float* ip;
    float* op;
    if (img < BB) { ip = ref + (size_t)img*64*HWSZ;      op = ref_t + (size_t)img*64*HWSZ; }
    else { int s = img - BB; ip = src + (size_t)s*64*HWSZ; op = src_t + (size_t)s*64*HWSZ; }
    int n0 = blockIdx.x * 64;
    int ln = threadIdx.x & 63, lr = threadIdx.x >> 6;
    #pragma unroll
    for (int i=0;i<16;++i) {
        int c = i*4 + lr;
        tb[c][ln] = ip[(size_t)c*HWSZ + n0 + ln];
    }
    __syncthreads();
    #pragma unroll
    for (int i=0;i<16;++i) {
        int n = i*4 + lr;
        op[(size_t)(n0+n)*64 + ln] = tb[ln][n];
    }
}

// ---------------- helpers ----------------
struct Taps {
    const float* p00; const float* p10; const float* p01; const float* p11;
    float t00, t10, t01, t11;
};

__device__ inline Taps mk_taps(const float* sp, float rx, float ry, float rz,
                               float depth, float t9, float t10, float t11) {
    float px = rx*depth + t9;
    float py = ry*depth + t10;
    float pz = rz*depth + t11;
    if (pz <= 0.001f) { px = (float)WW; py = (float)HH; pz = 1.f; }
    float ix = px/pz, iy = py/pz;
    float x0f = floorf(ix), y0f = floorf(iy);
    float wx1 = ix - x0f, wy1 = iy - y0f;
    float vx0 = (x0f      >= 0.f && x0f      <= (float)(WW-1)) ? 1.f : 0.f;
    float vx1 = (x0f+1.f  >= 0.f && x0f+1.f  <= (float)(WW-1)) ? 1.f : 0.f;
    float vy0 = (y0f      >= 0.f && y0f      <= (float)(HH-1)) ? 1.f : 0.f;
    float vy1 = (y0f+1.f  >= 0.f && y0f+1.f  <= (float)(HH-1)) ? 1.f : 0.f;
    Taps T;
    T.t00 = (1.f-wx1)*(1.f-wy1)*vx0*vy0;
    T.t10 = wx1*(1.f-wy1)*vx1*vy0;
    T.t01 = (1.f-wx1)*wy1*vx0*vy1;
    T.t11 = wx1*wy1*vx1*vy1;
    int x0c = (int)fminf(fmaxf(x0f,     0.f), (float)(WW-1));
    int x1c = (int)fminf(fmaxf(x0f+1.f, 0.f), (float)(WW-1));
    int y0c = (int)fminf(fmaxf(y0f,     0.f), (float)(HH-1));
    int y1c = (int)fminf(fmaxf(y0f+1.f, 0.f), (float)(HH-1));
    T.p00 = sp + (size_t)(y0c*WW + x0c)*64;
    T.p10 = sp + (size_t)(y0c*WW + x1c)*64;
    T.p01 = sp + (size_t)(y1c*WW + x0c)*64;
    T.p11 = sp + (size_t)(y1c*WW + x1c)*64;
    return T;
}

__device__ inline float dot8(float4 s0, float4 s1, float4 r0, float4 r1) {
    return s0.x*r0.x + s0.y*r0.y + s0.z*r0.z + s0.w*r0.w
         + s1.x*r1.x + s1.y*r1.y + s1.z*r1.z + s1.w*r1.w;
}

__device__ inline float tap_dot(const Taps& T, int g, float4 r0, float4 r1) {
    float4 a0 = *(const float4*)(T.p00 + g*8);
    float4 a1 = *(const float4*)(T.p00 + g*8 + 4);
    float4 b0 = *(const float4*)(T.p10 + g*8);
    float4 b1 = *(const float4*)(T.p10 + g*8 + 4);
    float4 c0 = *(const float4*)(T.p01 + g*8);
    float4 c1 = *(const float4*)(T.p01 + g*8 + 4);
    float4 e0 = *(const float4*)(T.p11 + g*8);
    float4 e1 = *(const float4*)(T.p11 + g*8 + 4);
    float d00 = dot8(a0,a1,r0,r1);
    float d10 = dot8(b0,b1,r0,r1);
    float d01 = dot8(c0,c1,r0,r1);
    float d11 = dot8(e0,e1,r0,r1);
    return T.t00*d00 + T.t10*d10 + T.t01*d01 + T.t11*d11;
}

// net layout: [0..127] w0(16x8), [128..143] b0, [144..271] w1(8x16),
//             [272..279] b1, [280..287] w2(1x8), [288] b2
__device__ inline float pixnet(const float* __restrict__ Wt, const float* sim) {
    float h0[16];
    #pragma unroll
    for (int o=0;o<16;++o) {
        float a = Wt[128+o];
        #pragma unroll
        for (int c=0;c<8;++c) a += Wt[o*8+c]*sim[c];
        h0[o] = fmaxf(a, 0.f);
    }
    float h1[8];
    #pragma unroll
    for (int o=0;o<8;++o) {
        float a = Wt[272+o];
        #pragma unroll
        for (int c=0;c<16;++c) a += Wt[144+o*16+c]*h0[c];
        h1[o] = fmaxf(a, 0.f);
    }
    float y = Wt[288];
    #pragma unroll
    for (int c=0;c<8;++c) y += Wt[280+c]*h1[c];
    return y;
}

// ---------------- main fused kernel: 2 depths per thread ----------------
// block = 256 = 32 pixels x 8 dL; thread handles depths dL and dL+8.
__global__ __launch_bounds__(256, 3) void eval_main_k(const float* __restrict__ ref_t,
                                                      const float* __restrict__ src_t,
                                                      const float* __restrict__ wsc,
                                                      const float* __restrict__ depth_sample,
                                                      float* __restrict__ s_buf,
                                                      float* __restrict__ vw_out) {
    __shared__ __align__(16) float refT[32][72];
    int tid  = threadIdx.x;
    int pixL = tid >> 3;
    int dL   = tid & 7;
    int pixG = blockIdx.x*32 + pixL;
    {   // cooperative ref tile load: thread (pixL, c8) loads 8 channels of its pixel
        int c8 = dL;
        const float* rp = ref_t + (size_t)pixG*64 + c8*8;
        float4 rv0 = *(const float4*)(rp);
        float4 rv1 = *(const float4*)(rp + 4);
        *(float4*)&refT[pixL][c8*8]     = rv0;
        *(float4*)&refT[pixL][c8*8 + 4] = rv1;
    }
    __syncthreads();

    int b  = pixG / HWSZ;
    int hw = pixG % HWSZ;
    int h  = hw / WW;
    int w  = hw % WW;
    const float* pw = wsc + 96;
    const float* sn = wsc + 385;
    float depth0 = depth_sample[((size_t)b*DD + dL    )*HWSZ + hw];
    float depth1 = depth_sample[((size_t)b*DD + dL + 8)*HWSZ + hw];
    float xf = (float)w, yf = (float)h;
    const float* rrow = &refT[pixL][0];

    float simsum0[8], simsum1[8];
    #pragma unroll
    for (int g=0; g<8; ++g) { simsum0[g] = 0.f; simsum1[g] = 0.f; }
    float wsum = 0.f;

    #pragma unroll
    for (int v=0; v<VV; ++v) {
        const float* pm = wsc + (v*BB + b)*12;     // wave-uniform -> s_load
        float rx = pm[0]*xf + pm[1]*yf + pm[2];
        float ry = pm[3]*xf + pm[4]*yf + pm[5];
        float rz = pm[6]*xf + pm[7]*yf + pm[8];
        const float* sp = src_t + (size_t)(v*BB + b)*HWSZ*64;
        Taps T0 = mk_taps(sp, rx, ry, rz, depth0, pm[9], pm[10], pm[11]);
        Taps T1 = mk_taps(sp, rx, ry, rz, depth1, pm[9], pm[10], pm[11]);

        float sim0[8], sim1[8];
        #pragma unroll
        for (int g=0; g<8; ++g) {
            float4 r0 = *(const float4*)(rrow + g*8);
            float4 r1 = *(const float4*)(rrow + g*8 + 4);
            sim0[g] = 0.125f * tap_dot(T0, g, r0, r1);
            sim1[g] = 0.125f * tap_dot(T1, g, r0, r1);
        }

        float y0 = pixnet(pw, sim0);
        float y1 = pixnet(pw, sim1);
        float sg0 = 1.f/(1.f + __expf(-y0));
        float sg1 = 1.f/(1.f + __expf(-y1));

        // max over the 16 depths of this pixel (2 local + 8 dL lanes)
        float vw = fmaxf(sg0, sg1);
        vw = fmaxf(vw, __shfl_xor(vw, 1));
        vw = fmaxf(vw, __shfl_xor(vw, 2));
        vw = fmaxf(vw, __shfl_xor(vw, 4));

        #pragma unroll
        for (int g=0; g<8; ++g) { simsum0[g] += sim0[g]*vw; simsum1[g] += sim1[g]*vw; }
        wsum += vw;
        if (dL == 0) vw_out[(size_t)(b*VV + v)*HWSZ + hw] = vw;
    }

    float invw = 1.f/wsum;
    float sa[8];
    #pragma unroll
    for (int g=0; g<8; ++g) sa[g] = simsum0[g]*invw;
    float s0 = pixnet(sn, sa);
    #pragma unroll
    for (int g=0; g<8; ++g) sa[g] = simsum1[g]*invw;
    float s1 = pixnet(sn, sa);

    s_buf[(size_t)pixG*DD + dL]     = s0;   // [B,HW,D] (D contiguous)
    s_buf[(size_t)pixG*DD + dL + 8] = s1;
}

// ---------------- final: grid_sample(s) + agg + softmax + depth ----------------
// block = 256 = 64 pixels x 4 j-threads; j handles nn in {j, j+4, j+8}.
__global__ __launch_bounds__(256) void eval_out_k(const float* __restrict__ s_buf,
                                                  const float* __restrict__ grid,
                                                  const float* __restrict__ weight,
                                                  const float* __restrict__ depth_sample,
                                                  const int* __restrict__ is_inverse,
                                                  float* __restrict__ out) {
    __shared__ float part[4][64][17];
    int tid = threadIdx.x;
    int px  = tid & 63;
    int j   = tid >> 6;
    int t   = blockIdx.x*64 + px;
    int b  = t / HWSZ;
    int hw = t % HWSZ;
    int h  = hw / WW;
    int w  = hw % WW;

    float agg[DD];
    #pragma unroll
    for (int d=0; d<DD; ++d) agg[d] = 0.f;

    #pragma unroll
    for (int k=0; k<3; ++k) {
        int nn = j + k*4;
        if (nn < NNB) {            // wave-uniform branch (wave = fixed j)
            const float* gp = grid + (((size_t)b*NNB*HH + nn*HH + h)*WW + w)*2;
            float gx = gp[0], gy = gp[1];
            float ix = ((gx+1.f)*WW - 1.f)*0.5f;
            float iy = ((gy+1.f)*HH - 1.f)*0.5f;
            float x0f = floorf(ix), y0f = floorf(iy);
            float wx1 = ix - x0f, wy1 = iy - y0f;
            int x0 = (int)x0f, y0 = (int)y0f;
            int x0c = x0 < 0 ? 0 : (x0 > WW-1 ? WW-1 : x0);
            int x1c = x0+1 < 0 ? 0 : (x0+1 > WW-1 ? WW-1 : x0+1);
            int y0c = y0 < 0 ? 0 : (y0 > HH-1 ? HH-1 : y0);
            int y1c = y0+1 < 0 ? 0 : (y0+1 > HH-1 ? HH-1 : y0+1);
            float w00 = (1.f-wx1)*(1.f-wy1), w10 = wx1*(1.f-wy1);
            float w01 = (1.f-wx1)*wy1,       w11 = wx1*wy1;
            const float* p00 = s_buf + ((size_t)b*HWSZ + y0c*WW + x0c)*DD;
            const float* p10 = s_buf + ((size_t)b*HWSZ + y0c*WW + x1c)*DD;
            const float* p01 = s_buf + ((size_t)b*HWSZ + y1c*WW + x0c)*DD;
            const float* p11 = s_buf + ((size_t)b*HWSZ + y1c*WW + x1c)*DD;
            const float* wp  = weight + ((size_t)b*DD*NNB + nn)*HWSZ + hw;
            #pragma unroll
            for (int q=0; q<4; ++q) {
                float4 v00 = *(const float4*)(p00 + q*4);
                float4 v10 = *(const float4*)(p10 + q*4);
                float4 v01 = *(const float4*)(p01 + q*4);
                float4 v11 = *(const float4*)(p11 + q*4);
                float s0 = w00*v00.x + w10*v10.x + w01*v01.x + w11*v11.x;
                float s1 = w00*v00.y + w10*v10.y + w01*v01.y + w11*v11.y;
                float s2 = w00*v00.z + w10*v10.z + w01*v01.z + w11*v11.z;
                float s3 = w00*v00.w + w10*v10.w + w01*v01.w + w11*v11.w;
                agg[q*4+0] += s0 * wp[(size_t)(q*4+0)*NNB*HWSZ];
                agg[q*4+1] += s1 * wp[(size_t)(q*4+1)*NNB*HWSZ];
                agg[q*4+2] += s2 * wp[(size_t)(q*4+2)*NNB*HWSZ];
                agg[q*4+3] += s3 * wp[(size_t)(q*4+3)*NNB*HWSZ];
            }
        }
    }

    #pragma unroll
    for (int d=0; d<DD; ++d) part[j][px][d] = agg[d];
    __syncthreads();
    if (j != 0) return;

    #pragma unroll
    for (int d=0; d<DD; ++d)
        agg[d] = part[0][px][d] + part[1][px][d] + part[2][px][d] + part[3][px][d];

    float m = agg[0];
    #pragma unroll
    for (int d=1; d<DD; ++d) m = fmaxf(m, agg[d]);
    float e[DD], sum = 0.f;
    #pragma unroll
    for (int d=0; d<DD; ++d) { e[d] = __expf(agg[d]-m); sum += e[d]; }
    float inv = 1.f/sum;

    const float* dsp = depth_sample + (size_t)b*DD*HWSZ + hw;
    float* sco = out + BB*HWSZ + (size_t)b*DD*HWSZ + hw;
    float dep = 0.f;
    if (*is_inverse) {
        float di = 0.f;
        #pragma unroll
        for (int d=0; d<DD; ++d) { float sc = e[d]*inv; sco[(size_t)d*HWSZ] = sc; di += (float)d*sc; }
        float invmin = 1.f/dsp[(size_t)(DD-1)*HWSZ];
        float invmax = 1.f/dsp[0];
        dep = 1.f/(invmax + di/(float)(DD-1)*(invmin-invmax));
    } else {
        #pragma unroll
        for (int d=0; d<DD; ++d) { float sc = e[d]*inv; sco[(size_t)d*HWSZ] = sc; dep += dsp[(size_t)d*HWSZ]*sc; }
    }
    out[t] = dep;   // depth [B,H,W]
}

extern "C" void kernel_launch(void* const* d_in, const int* in_sizes, int n_in,
                              void* d_out, int out_size, void* d_ws, size_t ws_size,
                              hipStream_t stream) {
    const float* ref_feature  = (const float*)d_in[0];
    const float* src_features = (const float*)d_in[1];
    const float* ref_proj     = (const float*)d_in[2];
    const float* src_projs    = (const float*)d_in[3];
    const float* depth_sample = (const float*)d_in[4];
    const float* grid         = (const float*)d_in[5];
    const float* weight       = (const float*)d_in[6];
    const float* pw_w0  = (const float*)d_in[7];
    const float* pw_g0  = (const float*)d_in[8];
    const float* pw_b0  = (const float*)d_in[9];
    const float* pw_w1  = (const float*)d_in[10];
    const float* pw_g1  = (const float*)d_in[11];
    const float* pw_b1  = (const float*)d_in[12];
    const float* pw_w2  = (const float*)d_in[13];
    const float* pw_c2b = (const float*)d_in[14];
    const float* sn_w0  = (const float*)d_in[15];
    const float* sn_g0  = (const float*)d_in[16];
    const float* sn_b0  = (const float*)d_in[17];
    const float* sn_w1  = (const float*)d_in[18];
    const float* sn_g1  = (const float*)d_in[19];
    const float* sn_b1  = (const float*)d_in[20];
    const float* sn_w2  = (const float*)d_in[21];
    const float* sn_c2b = (const float*)d_in[22];
    const int*   is_inverse = (const int*)d_in[23];
    float* out = (float*)d_out;

    float* ws    = (float*)d_ws;
    float* ref_t = ws + 1024;                              // B*HW*64
    float* src_t = ref_t + (size_t)BB*HWSZ*64;             // V*B*HW*64
    float* s_buf = src_t + (size_t)VV*BB*HWSZ*64;          // B*HW*D
    size_t need  = (size_t)(1024 + (size_t)BB*HWSZ*64 + (size_t)VV*BB*HWSZ*64 + (size_t)BB*HWSZ*DD)*sizeof(float);
    if (ws_size < need) return;  // workspace too small — cannot run

    prep_k<<<1, 128, 0, stream>>>(ref_proj, src_projs,
                                  pw_w0, pw_g0, pw_b0, pw_w1, pw_g1, pw_b1, pw_w2, pw_c2b,
                                  sn_w0, sn_g0, sn_b0, sn_w1, sn_g1, sn_b1, sn_w2, sn_c2b,
                                  ws);
    transpose2_k<<<dim3(HWSZ/64, BB + VV*BB), 256, 0, stream>>>(ref_feature, src_features,
                                                                ref_t, src_t);
    eval_main_k<<<(BB*HWSZ)/32, 256, 0, stream>>>(ref_t, src_t, ws, depth_sample,
                                                  s_buf, out + BB*HWSZ + BB*DD*HWSZ);
    eval_out_k<<<(BB*HWSZ)/64, 256, 0, stream>>>(s_buf, grid, weight, depth_sample,
                                                 is_inverse, out);
}

// Round 4
// 295.652 us; speedup vs baseline: 1.1841x; 1.1841x over previous
//
#include <hip/hip_runtime.h>
#include <math.h>

#define BB 2
#define CC 64
#define HH 128
#define WW 160
#define DD 16
#define VV 4
#define NNB 9
#define GG 8
#define HWSZ (HH*WW)
#define BNS 0.99999500003749977f  // 1/sqrt(1+1e-5)

// ---------------- 4x4 inverse (adjugate) ----------------
__device__ inline void inv4(const float* m, float* o) {
    float inv[16];
    inv[0]  =  m[5]*m[10]*m[15] - m[5]*m[11]*m[14] - m[9]*m[6]*m[15] + m[9]*m[7]*m[14] + m[13]*m[6]*m[11] - m[13]*m[7]*m[10];
    inv[4]  = -m[4]*m[10]*m[15] + m[4]*m[11]*m[14] + m[8]*m[6]*m[15] - m[8]*m[7]*m[14] - m[12]*m[6]*m[11] + m[12]*m[7]*m[10];
    inv[8]  =  m[4]*m[9]*m[15]  - m[4]*m[11]*m[13] - m[8]*m[5]*m[15] + m[8]*m[7]*m[13] + m[12]*m[5]*m[11] - m[12]*m[7]*m[9];
    inv[12] = -m[4]*m[9]*m[14]  + m[4]*m[10]*m[13] + m[8]*m[5]*m[14] - m[8]*m[6]*m[13] - m[12]*m[5]*m[10] + m[12]*m[6]*m[9];
    inv[1]  = -m[1]*m[10]*m[15] + m[1]*m[11]*m[14] + m[9]*m[2]*m[15] - m[9]*m[3]*m[14] - m[13]*m[2]*m[11] + m[13]*m[3]*m[10];
    inv[5]  =  m[0]*m[10]*m[15] - m[0]*m[11]*m[14] - m[8]*m[2]*m[15] + m[8]*m[3]*m[14] + m[12]*m[2]*m[11] - m[12]*m[3]*m[10];
    inv[9]  = -m[0]*m[9]*m[15]  + m[0]*m[11]*m[13] + m[8]*m[1]*m[15] - m[8]*m[3]*m[13] - m[12]*m[1]*m[11] + m[12]*m[3]*m[9];
    inv[13] =  m[0]*m[9]*m[14]  - m[0]*m[10]*m[13] - m[8]*m[1]*m[14] + m[8]*m[2]*m[13] + m[12]*m[1]*m[10] - m[12]*m[2]*m[9];
    inv[2]  =  m[1]*m[6]*m[15]  - m[1]*m[7]*m[14]  - m[5]*m[2]*m[15] + m[5]*m[3]*m[14] + m[13]*m[2]*m[7]  - m[13]*m[3]*m[6];
    inv[6]  = -m[0]*m[6]*m[15]  + m[0]*m[7]*m[14]  + m[4]*m[2]*m[15] - m[4]*m[3]*m[14] - m[12]*m[2]*m[7]  + m[12]*m[3]*m[6];
    inv[10] =  m[0]*m[5]*m[15]  - m[0]*m[7]*m[13]  - m[4]*m[1]*m[15] + m[4]*m[3]*m[13] + m[12]*m[1]*m[7]  - m[12]*m[3]*m[5];
    inv[14] = -m[0]*m[5]*m[14]  + m[0]*m[6]*m[13]  + m[4]*m[1]*m[14] - m[4]*m[2]*m[13] - m[12]*m[1]*m[6]  + m[12]*m[2]*m[5];
    inv[3]  = -m[1]*m[6]*m[11]  + m[1]*m[7]*m[10]  + m[5]*m[2]*m[11] - m[5]*m[3]*m[10] - m[9]*m[2]*m[7]   + m[9]*m[3]*m[6];
    inv[7]  =  m[0]*m[6]*m[11]  - m[0]*m[7]*m[10]  - m[4]*m[2]*m[11] + m[4]*m[3]*m[10] + m[8]*m[2]*m[7]   - m[8]*m[3]*m[6];
    inv[11] = -m[0]*m[5]*m[11]  + m[0]*m[7]*m[9]   + m[4]*m[1]*m[11] - m[4]*m[3]*m[9]  - m[8]*m[1]*m[7]   + m[8]*m[3]*m[5];
    inv[15] =  m[0]*m[5]*m[10]  - m[0]*m[6]*m[9]   - m[4]*m[1]*m[10] + m[4]*m[2]*m[9]  + m[8]*m[1]*m[6]   - m[8]*m[2]*m[5];
    float det = m[0]*inv[0] + m[1]*inv[4] + m[2]*inv[8] + m[3]*inv[12];
    det = 1.0f/det;
    #pragma unroll
    for (int i=0;i<16;++i) o[i] = inv[i]*det;
}

// ---------------- prep: proj matrices + folded net weights ----------------
// ws layout (floats): [0..95] proj (V*B x 12), [96..384] pw net, [385..673] sn net
__global__ void prep_k(const float* __restrict__ ref_proj, const float* __restrict__ src_projs,
                       const float* __restrict__ pw_w0, const float* __restrict__ pw_g0, const float* __restrict__ pw_b0,
                       const float* __restrict__ pw_w1, const float* __restrict__ pw_g1, const float* __restrict__ pw_b1,
                       const float* __restrict__ pw_w2, const float* __restrict__ pw_c2b,
                       const float* __restrict__ sn_w0, const float* __restrict__ sn_g0, const float* __restrict__ sn_b0,
                       const float* __restrict__ sn_w1, const float* __restrict__ sn_g1, const float* __restrict__ sn_b1,
                       const float* __restrict__ sn_w2, const float* __restrict__ sn_c2b,
                       float* __restrict__ ws) {
    int t = threadIdx.x;
    if (t < VV*BB) {
        int b = t % BB;
        float Mi[16];
        inv4(ref_proj + b*16, Mi);
        const float* A = src_projs + t*16;
        float P[16];
        #pragma unroll
        for (int i=0;i<4;++i)
            #pragma unroll
            for (int j=0;j<4;++j) {
                float s = 0.f;
                #pragma unroll
                for (int k=0;k<4;++k) s += A[i*4+k]*Mi[k*4+j];
                P[i*4+j] = s;
            }
        float* o = ws + t*12;
        o[0]=P[0]; o[1]=P[1]; o[2]=P[2];
        o[3]=P[4]; o[4]=P[5]; o[5]=P[6];
        o[6]=P[8]; o[7]=P[9]; o[8]=P[10];
        o[9]=P[3]; o[10]=P[7]; o[11]=P[11];
    }
    if (t < 128) {
        ws[96 + t]        = pw_w0[t]*pw_g0[t>>3]*BNS;
        ws[96 + 144 + t]  = pw_w1[t]*pw_g1[t>>4]*BNS;
        ws[385 + t]       = sn_w0[t]*sn_g0[t>>3]*BNS;
        ws[385 + 144 + t] = sn_w1[t]*sn_g1[t>>4]*BNS;
    }
    if (t < 16) { ws[96+128+t]=pw_b0[t]; ws[385+128+t]=sn_b0[t]; }
    if (t < 8)  { ws[96+272+t]=pw_b1[t]; ws[96+280+t]=pw_w2[t];
                  ws[385+272+t]=sn_b1[t]; ws[385+280+t]=sn_w2[t]; }
    if (t == 0) { ws[96+288]=pw_c2b[0]; ws[385+288]=sn_c2b[0]; }
}

// ---------------- combined transpose [img][64][HW] -> [img][HW][64] ----------------
__global__ __launch_bounds__(256) void transpose2_k(const float* __restrict__ ref,
                                                    const float* __restrict__ src,
                                                    float* __restrict__ ref_t,
                                                    float* __restrict__ src_t) {
    __shared__ float tb[64][65];
    int img = blockIdx.y;
    const float* ip;
    float* op;
    if (img < BB) { ip = ref + (size_t)img*64*HWSZ;      op = ref_t + (size_t)img*64*HWSZ; }
    else { int s = img - BB; ip = src + (size_t)s*64*HWSZ; op = src_t + (size_t)s*64*HWSZ; }
    int n0 = blockIdx.x * 64;
    int ln = threadIdx.x & 63, lr = threadIdx.x >> 6;
    #pragma unroll
    for (int i=0;i<16;++i) {
        int c = i*4 + lr;
        tb[c][ln] = ip[(size_t)c*HWSZ + n0 + ln];
    }
    __syncthreads();
    #pragma unroll
    for (int i=0;i<16;++i) {
        int n = i*4 + lr;
        op[(size_t)(n0+n)*64 + ln] = tb[ln][n];
    }
}

__device__ inline float dot8(float4 s0, float4 s1, float4 r0, float4 r1) {
    return s0.x*r0.x + s0.y*r0.y + s0.z*r0.z + s0.w*r0.w
         + s1.x*r1.x + s1.y*r1.y + s1.z*r1.z + s1.w*r1.w;
}

// ---------------- main fused kernel (r2 structure: 1 depth per thread) ----------------
// block = 256 threads = 16 pixels x 16 depths.
__global__ __launch_bounds__(256) void eval_main_k(const float* __restrict__ ref_t,
                                                   const float* __restrict__ src_t,
                                                   const float* __restrict__ wsc,
                                                   const float* __restrict__ depth_sample,
                                                   float* __restrict__ s_buf,
                                                   float* __restrict__ vw_out) {
    __shared__ float refT[16][72];
    int tid  = threadIdx.x;
    int pixL = tid >> 4;
    int d    = tid & 15;
    int pixG = blockIdx.x*16 + pixL;
    {   // cooperative ref tile load: thread (pixL, c4) loads 4 channels
        int c4 = tid & 15;
        float4 rv = *(const float4*)(ref_t + (size_t)pixG*64 + c4*4);
        refT[pixL][c4*4+0] = rv.x; refT[pixL][c4*4+1] = rv.y;
        refT[pixL][c4*4+2] = rv.z; refT[pixL][c4*4+3] = rv.w;
    }
    __syncthreads();

    int b  = pixG / HWSZ;
    int hw = pixG % HWSZ;
    int h  = hw / WW;
    int w  = hw % WW;
    const float* pw = wsc + 96;
    const float* sn = wsc + 385;
    float depth = depth_sample[((size_t)b*DD + d)*HWSZ + hw];
    float xf = (float)w, yf = (float)h;
    const float* rrow = &refT[pixL][0];

    float simsum[8];
    #pragma unroll
    for (int g=0; g<8; ++g) simsum[g] = 0.f;
    float wsum = 0.f;

    #pragma unroll
    for (int v=0; v<VV; ++v) {
        const float* pm = wsc + (v*BB + b)*12;   // wave-uniform -> s_load
        float rx = pm[0]*xf + pm[1]*yf + pm[2];
        float ry = pm[3]*xf + pm[4]*yf + pm[5];
        float rz = pm[6]*xf + pm[7]*yf + pm[8];
        float px = rx*depth + pm[9];
        float py = ry*depth + pm[10];
        float pz = rz*depth + pm[11];
        if (pz <= 0.001f) { px = (float)WW; py = (float)HH; pz = 1.f; }
        float ix = px/pz, iy = py/pz;
        float x0f = floorf(ix), y0f = floorf(iy);
        float wx1 = ix - x0f, wy1 = iy - y0f;
        float vx0 = (x0f      >= 0.f && x0f      <= (float)(WW-1)) ? 1.f : 0.f;
        float vx1 = (x0f+1.f  >= 0.f && x0f+1.f  <= (float)(WW-1)) ? 1.f : 0.f;
        float vy0 = (y0f      >= 0.f && y0f      <= (float)(HH-1)) ? 1.f : 0.f;
        float vy1 = (y0f+1.f  >= 0.f && y0f+1.f  <= (float)(HH-1)) ? 1.f : 0.f;
        float tw00 = (1.f-wx1)*(1.f-wy1)*vx0*vy0;
        float tw10 = wx1*(1.f-wy1)*vx1*vy0;
        float tw01 = (1.f-wx1)*wy1*vx0*vy1;
        float tw11 = wx1*wy1*vx1*vy1;
        int x0c = (int)fminf(fmaxf(x0f,     0.f), (float)(WW-1));
        int x1c = (int)fminf(fmaxf(x0f+1.f, 0.f), (float)(WW-1));
        int y0c = (int)fminf(fmaxf(y0f,     0.f), (float)(HH-1));
        int y1c = (int)fminf(fmaxf(y0f+1.f, 0.f), (float)(HH-1));

        const float* sp  = src_t + (size_t)(v*BB + b)*HWSZ*64;
        const float* p00 = sp + (size_t)(y0c*WW + x0c)*64;
        const float* p10 = sp + (size_t)(y0c*WW + x1c)*64;
        const float* p01 = sp + (size_t)(y1c*WW + x0c)*64;
        const float* p11 = sp + (size_t)(y1c*WW + x1c)*64;

        float sim[8];
        #pragma unroll
        for (int g=0; g<8; ++g) {
            float4 r0 = *(const float4*)(rrow + g*8);
            float4 r1 = *(const float4*)(rrow + g*8 + 4);
            float4 a0 = *(const float4*)(p00 + g*8);
            float4 a1 = *(const float4*)(p00 + g*8 + 4);
            float4 b0 = *(const float4*)(p10 + g*8);
            float4 b1 = *(const float4*)(p10 + g*8 + 4);
            float4 c0 = *(const float4*)(p01 + g*8);
            float4 c1 = *(const float4*)(p01 + g*8 + 4);
            float4 e0 = *(const float4*)(p11 + g*8);
            float4 e1 = *(const float4*)(p11 + g*8 + 4);
            float d00 = dot8(a0,a1,r0,r1);
            float d10 = dot8(b0,b1,r0,r1);
            float d01 = dot8(c0,c1,r0,r1);
            float d11 = dot8(e0,e1,r0,r1);
            sim[g] = 0.125f*(tw00*d00 + tw10*d10 + tw01*d01 + tw11*d11);
        }

        // pixel-wise net 8->16->8->1, sigmoid
        float h0[16];
        #pragma unroll
        for (int o=0;o<16;++o) {
            float a = pw[128+o];
            #pragma unroll
            for (int c=0;c<8;++c) a += pw[o*8+c]*sim[c];
            h0[o] = fmaxf(a, 0.f);
        }
        float h1[8];
        #pragma unroll
        for (int o=0;o<8;++o) {
            float a = pw[272+o];
            #pragma unroll
            for (int c=0;c<16;++c) a += pw[144+o*16+c]*h0[c];
            h1[o] = fmaxf(a, 0.f);
        }
        float y = pw[288];
        #pragma unroll
        for (int c=0;c<8;++c) y += pw[280+c]*h1[c];
        float sg = 1.f/(1.f + __expf(-y));

        // max over the 16 depth lanes of this pixel
        float vw = sg;
        vw = fmaxf(vw, __shfl_xor(vw, 1));
        vw = fmaxf(vw, __shfl_xor(vw, 2));
        vw = fmaxf(vw, __shfl_xor(vw, 4));
        vw = fmaxf(vw, __shfl_xor(vw, 8));

        #pragma unroll
        for (int g=0; g<8; ++g) simsum[g] += sim[g]*vw;
        wsum += vw;
        if (d == 0) vw_out[(size_t)(b*VV + v)*HWSZ + hw] = vw;
    }

    float invw = 1.f/wsum;
    float sa[8];
    #pragma unroll
    for (int g=0; g<8; ++g) sa[g] = simsum[g]*invw;

    // score net 8->16->8->1
    float q0[16];
    #pragma unroll
    for (int o=0;o<16;++o) {
        float a = sn[128+o];
        #pragma unroll
        for (int c=0;c<8;++c) a += sn[o*8+c]*sa[c];
        q0[o] = fmaxf(a, 0.f);
    }
    float q1[8];
    #pragma unroll
    for (int o=0;o<8;++o) {
        float a = sn[272+o];
        #pragma unroll
        for (int c=0;c<16;++c) a += sn[144+o*16+c]*q0[c];
        q1[o] = fmaxf(a, 0.f);
    }
    float s = sn[288];
    #pragma unroll
    for (int c=0;c<8;++c) s += sn[280+c]*q1[c];

    s_buf[(size_t)pixG*DD + d] = s;   // [B,HW,D] (D contiguous)
}

// ---------------- final: grid_sample(s) + agg + softmax + depth ----------------
// block = 256 = 64 pixels x 4 j-threads; j handles nn in {j, j+4, j+8}.
__global__ __launch_bounds__(256) void eval_out_k(const float* __restrict__ s_buf,
                                                  const float* __restrict__ grid,
                                                  const float* __restrict__ weight,
                                                  const float* __restrict__ depth_sample,
                                                  const int* __restrict__ is_inverse,
                                                  float* __restrict__ out) {
    __shared__ float part[4][64][17];
    int tid = threadIdx.x;
    int px  = tid & 63;
    int j   = tid >> 6;
    int t   = blockIdx.x*64 + px;
    int b  = t / HWSZ;
    int hw = t % HWSZ;
    int h  = hw / WW;
    int w  = hw % WW;

    float agg[DD];
    #pragma unroll
    for (int d=0; d<DD; ++d) agg[d] = 0.f;

    #pragma unroll
    for (int k=0; k<3; ++k) {
        int nn = j + k*4;
        if (nn < NNB) {            // wave-uniform branch (wave = fixed j)
            const float* gp = grid + (((size_t)b*NNB*HH + nn*HH + h)*WW + w)*2;
            float gx = gp[0], gy = gp[1];
            float ix = ((gx+1.f)*WW - 1.f)*0.5f;
            float iy = ((gy+1.f)*HH - 1.f)*0.5f;
            float x0f = floorf(ix), y0f = floorf(iy);
            float wx1 = ix - x0f, wy1 = iy - y0f;
            int x0 = (int)x0f, y0 = (int)y0f;
            int x0c = x0 < 0 ? 0 : (x0 > WW-1 ? WW-1 : x0);
            int x1c = x0+1 < 0 ? 0 : (x0+1 > WW-1 ? WW-1 : x0+1);
            int y0c = y0 < 0 ? 0 : (y0 > HH-1 ? HH-1 : y0);
            int y1c = y0+1 < 0 ? 0 : (y0+1 > HH-1 ? HH-1 : y0+1);
            float w00 = (1.f-wx1)*(1.f-wy1), w10 = wx1*(1.f-wy1);
            float w01 = (1.f-wx1)*wy1,       w11 = wx1*wy1;
            const float* p00 = s_buf + ((size_t)b*HWSZ + y0c*WW + x0c)*DD;
            const float* p10 = s_buf + ((size_t)b*HWSZ + y0c*WW + x1c)*DD;
            const float* p01 = s_buf + ((size_t)b*HWSZ + y1c*WW + x0c)*DD;
            const float* p11 = s_buf + ((size_t)b*HWSZ + y1c*WW + x1c)*DD;
            const float* wp  = weight + ((size_t)b*DD*NNB + nn)*HWSZ + hw;
            #pragma unroll
            for (int q=0; q<4; ++q) {
                float4 v00 = *(const float4*)(p00 + q*4);
                float4 v10 = *(const float4*)(p10 + q*4);
                float4 v01 = *(const float4*)(p01 + q*4);
                float4 v11 = *(const float4*)(p11 + q*4);
                float s0 = w00*v00.x + w10*v10.x + w01*v01.x + w11*v11.x;
                float s1 = w00*v00.y + w10*v10.y + w01*v01.y + w11*v11.y;
                float s2 = w00*v00.z + w10*v10.z + w01*v01.z + w11*v11.z;
                float s3 = w00*v00.w + w10*v10.w + w01*v01.w + w11*v11.w;
                agg[q*4+0] += s0 * wp[(size_t)(q*4+0)*NNB*HWSZ];
                agg[q*4+1] += s1 * wp[(size_t)(q*4+1)*NNB*HWSZ];
                agg[q*4+2] += s2 * wp[(size_t)(q*4+2)*NNB*HWSZ];
                agg[q*4+3] += s3 * wp[(size_t)(q*4+3)*NNB*HWSZ];
            }
        }
    }

    #pragma unroll
    for (int d=0; d<DD; ++d) part[j][px][d] = agg[d];
    __syncthreads();
    if (j != 0) return;

    #pragma unroll
    for (int d=0; d<DD; ++d)
        agg[d] = part[0][px][d] + part[1][px][d] + part[2][px][d] + part[3][px][d];

    float m = agg[0];
    #pragma unroll
    for (int d=1; d<DD; ++d) m = fmaxf(m, agg[d]);
    float e[DD], sum = 0.f;
    #pragma unroll
    for (int d=0; d<DD; ++d) { e[d] = __expf(agg[d]-m); sum += e[d]; }
    float inv = 1.f/sum;

    const float* dsp = depth_sample + (size_t)b*DD*HWSZ + hw;
    float* sco = out + BB*HWSZ + (size_t)b*DD*HWSZ + hw;
    float dep = 0.f;
    if (*is_inverse) {
        float di = 0.f;
        #pragma unroll
        for (int d=0; d<DD; ++d) { float sc = e[d]*inv; sco[(size_t)d*HWSZ] = sc; di += (float)d*sc; }
        float invmin = 1.f/dsp[(size_t)(DD-1)*HWSZ];
        float invmax = 1.f/dsp[0];
        dep = 1.f/(invmax + di/(float)(DD-1)*(invmin-invmax));
    } else {
        #pragma unroll
        for (int d=0; d<DD; ++d) { float sc = e[d]*inv; sco[(size_t)d*HWSZ] = sc; dep += dsp[(size_t)d*HWSZ]*sc; }
    }
    out[t] = dep;   // depth [B,H,W]
}

extern "C" void kernel_launch(void* const* d_in, const int* in_sizes, int n_in,
                              void* d_out, int out_size, void* d_ws, size_t ws_size,
                              hipStream_t stream) {
    const float* ref_feature  = (const float*)d_in[0];
    const float* src_features = (const float*)d_in[1];
    const float* ref_proj     = (const float*)d_in[2];
    const float* src_projs    = (const float*)d_in[3];
    const float* depth_sample = (const float*)d_in[4];
    const float* grid         = (const float*)d_in[5];
    const float* weight       = (const float*)d_in[6];
    const float* pw_w0  = (const float*)d_in[7];
    const float* pw_g0  = (const float*)d_in[8];
    const float* pw_b0  = (const float*)d_in[9];
    const float* pw_w1  = (const float*)d_in[10];
    const float* pw_g1  = (const float*)d_in[11];
    const float* pw_b1  = (const float*)d_in[12];
    const float* pw_w2  = (const float*)d_in[13];
    const float* pw_c2b = (const float*)d_in[14];
    const float* sn_w0  = (const float*)d_in[15];
    const float* sn_g0  = (const float*)d_in[16];
    const float* sn_b0  = (const float*)d_in[17];
    const float* sn_w1  = (const float*)d_in[18];
    const float* sn_g1  = (const float*)d_in[19];
    const float* sn_b1  = (const float*)d_in[20];
    const float* sn_w2  = (const float*)d_in[21];
    const float* sn_c2b = (const float*)d_in[22];
    const int*   is_inverse = (const int*)d_in[23];
    float* out = (float*)d_out;

    float* ws    = (float*)d_ws;
    float* ref_t = ws + 1024;                              // B*HW*64
    float* src_t = ref_t + (size_t)BB*HWSZ*64;             // V*B*HW*64
    float* s_buf = src_t + (size_t)VV*BB*HWSZ*64;          // B*HW*D
    size_t need  = (size_t)(1024 + (size_t)BB*HWSZ*64 + (size_t)VV*BB*HWSZ*64 + (size_t)BB*HWSZ*DD)*sizeof(float);
    if (ws_size < need) return;  // workspace too small — cannot run

    prep_k<<<1, 128, 0, stream>>>(ref_proj, src_projs,
                                  pw_w0, pw_g0, pw_b0, pw_w1, pw_g1, pw_b1, pw_w2, pw_c2b,
                                  sn_w0, sn_g0, sn_b0, sn_w1, sn_g1, sn_b1, sn_w2, sn_c2b,
                                  ws);
    transpose2_k<<<dim3(HWSZ/64, BB + VV*BB), 256, 0, stream>>>(ref_feature, src_features,
                                                                ref_t, src_t);
    eval_main_k<<<(BB*HWSZ)/16, 256, 0, stream>>>(ref_t, src_t, ws, depth_sample,
                                                  s_buf, out + BB*HWSZ + BB*DD*HWSZ);
    eval_out_k<<<(BB*HWSZ)/64, 256, 0, stream>>>(s_buf, grid, weight, depth_sample,
                                                 is_inverse, out);
}

// Round 8
// 253.026 us; speedup vs baseline: 1.3836x; 1.1685x over previous
//
#include <hip/hip_runtime.h>
#include <math.h>

#define BB 2
#define CC 64
#define HH 128
#define WW 160
#define DD 16
#define VV 4
#define NNB 9
#define GG 8
#define HWSZ (HH*WW)
#define BNS 0.99999500003749977f  // 1/sqrt(1+1e-5)

typedef _Float16 half2_t __attribute__((ext_vector_type(2)));

__device__ inline half2_t as_h2(unsigned u){ union { unsigned u; half2_t h; } x; x.u = u; return x.h; }
__device__ inline unsigned as_u(half2_t h){ union { unsigned u; half2_t h; } x; x.h = h; return x.u; }

// fp16 8-element dot with fp32 accumulate via v_dot2_f32_f16
__device__ inline float dot8h(uint4 a, uint4 r) {
    float s = __builtin_amdgcn_fdot2(as_h2(a.x), as_h2(r.x), 0.f, false);
    s = __builtin_amdgcn_fdot2(as_h2(a.y), as_h2(r.y), s, false);
    s = __builtin_amdgcn_fdot2(as_h2(a.z), as_h2(r.z), s, false);
    s = __builtin_amdgcn_fdot2(as_h2(a.w), as_h2(r.w), s, false);
    return s;
}

// ---------------- 4x4 inverse (adjugate) ----------------
__device__ inline void inv4(const float* m, float* o) {
    float inv[16];
    inv[0]  =  m[5]*m[10]*m[15] - m[5]*m[11]*m[14] - m[9]*m[6]*m[15] + m[9]*m[7]*m[14] + m[13]*m[6]*m[11] - m[13]*m[7]*m[10];
    inv[4]  = -m[4]*m[10]*m[15] + m[4]*m[11]*m[14] + m[8]*m[6]*m[15] - m[8]*m[7]*m[14] - m[12]*m[6]*m[11] + m[12]*m[7]*m[10];
    inv[8]  =  m[4]*m[9]*m[15]  - m[4]*m[11]*m[13] - m[8]*m[5]*m[15] + m[8]*m[7]*m[13] + m[12]*m[5]*m[11] - m[12]*m[7]*m[9];
    inv[12] = -m[4]*m[9]*m[14]  + m[4]*m[10]*m[13] + m[8]*m[5]*m[14] - m[8]*m[6]*m[13] - m[12]*m[5]*m[10] + m[12]*m[6]*m[9];
    inv[1]  = -m[1]*m[10]*m[15] + m[1]*m[11]*m[14] + m[9]*m[2]*m[15] - m[9]*m[3]*m[14] - m[13]*m[2]*m[11] + m[13]*m[3]*m[10];
    inv[5]  =  m[0]*m[10]*m[15] - m[0]*m[11]*m[14] - m[8]*m[2]*m[15] + m[8]*m[3]*m[14] + m[12]*m[2]*m[11] - m[12]*m[3]*m[10];
    inv[9]  = -m[0]*m[9]*m[15]  + m[0]*m[11]*m[13] + m[8]*m[1]*m[15] - m[8]*m[3]*m[13] - m[12]*m[1]*m[11] + m[12]*m[3]*m[9];
    inv[13] =  m[0]*m[9]*m[14]  - m[0]*m[10]*m[13] - m[8]*m[1]*m[14] + m[8]*m[2]*m[13] + m[12]*m[1]*m[10] - m[12]*m[2]*m[9];
    inv[2]  =  m[1]*m[6]*m[15]  - m[1]*m[7]*m[14]  - m[5]*m[2]*m[15] + m[5]*m[3]*m[14] + m[13]*m[2]*m[7]  - m[13]*m[3]*m[6];
    inv[6]  = -m[0]*m[6]*m[15]  + m[0]*m[7]*m[14]  + m[4]*m[2]*m[15] - m[4]*m[3]*m[14] - m[12]*m[2]*m[7]  + m[12]*m[3]*m[6];
    inv[10] =  m[0]*m[5]*m[15]  - m[0]*m[7]*m[13]  - m[4]*m[1]*m[15] + m[4]*m[3]*m[13] + m[12]*m[1]*m[7]  - m[12]*m[3]*m[5];
    inv[14] = -m[0]*m[5]*m[14]  + m[0]*m[6]*m[13]  + m[4]*m[1]*m[14] - m[4]*m[2]*m[13] - m[12]*m[1]*m[6]  + m[12]*m[2]*m[5];
    inv[3]  = -m[1]*m[6]*m[11]  + m[1]*m[7]*m[10]  + m[5]*m[2]*m[11] - m[5]*m[3]*m[10] - m[9]*m[2]*m[7]   + m[9]*m[3]*m[6];
    inv[7]  =  m[0]*m[6]*m[11]  - m[0]*m[7]*m[10]  - m[4]*m[2]*m[11] + m[4]*m[3]*m[10] + m[8]*m[2]*m[7]   - m[8]*m[3]*m[6];
    inv[11] = -m[0]*m[5]*m[11]  + m[0]*m[7]*m[9]   + m[4]*m[1]*m[11] - m[4]*m[3]*m[9]  - m[8]*m[1]*m[7]   + m[8]*m[3]*m[5];
    inv[15] =  m[0]*m[5]*m[10]  - m[0]*m[6]*m[9]   - m[4]*m[1]*m[10] + m[4]*m[2]*m[9]  + m[8]*m[1]*m[6]   - m[8]*m[2]*m[5];
    float det = m[0]*inv[0] + m[1]*inv[4] + m[2]*inv[8] + m[3]*inv[12];
    det = 1.0f/det;
    #pragma unroll
    for (int i=0;i<16;++i) o[i] = inv[i]*det;
}

// ---------------- prep: proj matrices + folded net weights ----------------
// ws layout (floats): [0..95] proj (V*B x 12), [96..384] pw net, [385..673] sn net
__global__ void prep_k(const float* __restrict__ ref_proj, const float* __restrict__ src_projs,
                       const float* __restrict__ pw_w0, const float* __restrict__ pw_g0, const float* __restrict__ pw_b0,
                       const float* __restrict__ pw_w1, const float* __restrict__ pw_g1, const float* __restrict__ pw_b1,
                       const float* __restrict__ pw_w2, const float* __restrict__ pw_c2b,
                       const float* __restrict__ sn_w0, const float* __restrict__ sn_g0, const float* __restrict__ sn_b0,
                       const float* __restrict__ sn_w1, const float* __restrict__ sn_g1, const float* __restrict__ sn_b1,
                       const float* __restrict__ sn_w2, const float* __restrict__ sn_c2b,
                       float* __restrict__ ws) {
    int t = threadIdx.x;
    if (t < VV*BB) {
        int b = t % BB;
        float Mi[16];
        inv4(ref_proj + b*16, Mi);
        const float* A = src_projs + t*16;
        float P[16];
        #pragma unroll
        for (int i=0;i<4;++i)
            #pragma unroll
            for (int j=0;j<4;++j) {
                float s = 0.f;
                #pragma unroll
                for (int k=0;k<4;++k) s += A[i*4+k]*Mi[k*4+j];
                P[i*4+j] = s;
            }
        float* o = ws + t*12;
        o[0]=P[0]; o[1]=P[1]; o[2]=P[2];
        o[3]=P[4]; o[4]=P[5]; o[5]=P[6];
        o[6]=P[8]; o[7]=P[9]; o[8]=P[10];
        o[9]=P[3]; o[10]=P[7]; o[11]=P[11];
    }
    if (t < 128) {
        ws[96 + t]        = pw_w0[t]*pw_g0[t>>3]*BNS;
        ws[96 + 144 + t]  = pw_w1[t]*pw_g1[t>>4]*BNS;
        ws[385 + t]       = sn_w0[t]*sn_g0[t>>3]*BNS;
        ws[385 + 144 + t] = sn_w1[t]*sn_g1[t>>4]*BNS;
    }
    if (t < 16) { ws[96+128+t]=pw_b0[t]; ws[385+128+t]=sn_b0[t]; }
    if (t < 8)  { ws[96+272+t]=pw_b1[t]; ws[96+280+t]=pw_w2[t];
                  ws[385+272+t]=sn_b1[t]; ws[385+280+t]=sn_w2[t]; }
    if (t == 0) { ws[96+288]=pw_c2b[0]; ws[385+288]=sn_c2b[0]; }
}

// ---------------- transpose src [img][64][HW] -> fp16 [img][HW][64] ----------------
// 64px x 64ch tile per block; float4 global loads, half4 (uint2) stores.
__global__ __launch_bounds__(256) void transpose_h_k(const float* __restrict__ src,
                                                     _Float16* __restrict__ dst) {
    __shared__ float tb[64][65];
    int img = blockIdx.y;
    int n0  = blockIdx.x * 64;
    const float* ip = src + (size_t)img*64*HWSZ;
    _Float16*    op = dst + (size_t)img*HWSZ*64;
    int tid = threadIdx.x;
    #pragma unroll
    for (int i=0;i<4;++i) {
        int idx = i*256 + tid;
        int c  = idx >> 4;        // channel 0..63 (16 lanes share one c)
        int p4 = idx & 15;        // px-quad
        float4 v = *(const float4*)(ip + (size_t)c*HWSZ + n0 + p4*4);
        tb[c][p4*4+0]=v.x; tb[c][p4*4+1]=v.y; tb[c][p4*4+2]=v.z; tb[c][p4*4+3]=v.w;
    }
    __syncthreads();
    #pragma unroll
    for (int i=0;i<4;++i) {
        int idx = i*256 + tid;
        int n  = idx >> 4;        // px 0..63
        int cq = idx & 15;        // channel-quad
        half2_t h0 = { (_Float16)tb[cq*4+0][n], (_Float16)tb[cq*4+1][n] };
        half2_t h1 = { (_Float16)tb[cq*4+2][n], (_Float16)tb[cq*4+3][n] };
        uint2 u; u.x = as_u(h0); u.y = as_u(h1);
        *(uint2*)(op + (size_t)(n0+n)*64 + cq*4) = u;
    }
}

// net layout: [0..127] w0(16x8), [128..143] b0, [144..271] w1(8x16),
//             [272..279] b1, [280..287] w2(1x8), [288] b2
__device__ inline float pixnet(const float* __restrict__ Wt, const float* sim) {
    float h0[16];
    #pragma unroll
    for (int o=0;o<16;++o) {
        float a = Wt[128+o];
        #pragma unroll
        for (int c=0;c<8;++c) a += Wt[o*8+c]*sim[c];
        h0[o] = fmaxf(a, 0.f);
    }
    float h1[8];
    #pragma unroll
    for (int o=0;o<8;++o) {
        float a = Wt[272+o];
        #pragma unroll
        for (int c=0;c<16;++c) a += Wt[144+o*16+c]*h0[c];
        h1[o] = fmaxf(a, 0.f);
    }
    float y = Wt[288];
    #pragma unroll
    for (int c=0;c<8;++c) y += Wt[280+c]*h1[c];
    return y;
}

// ---------------- main fused kernel (fp16 gather, 1 depth/thread) ----------------
// block = 256 threads = 16 pixels x 16 depths.
__global__ __launch_bounds__(256) void eval_main_k(const float* __restrict__ ref_f,
                                                   const unsigned* __restrict__ src_u,
                                                   const float* __restrict__ wsc,
                                                   const float* __restrict__ depth_sample,
                                                   float* __restrict__ s_buf,
                                                   float* __restrict__ vw_out) {
    __shared__ __align__(16) unsigned refU[16][36];   // 16 px x 64ch fp16 (32 uints, pad 36)
    int tid  = threadIdx.x;
    int pixL = tid >> 4;
    int d    = tid & 15;
    int pixG = blockIdx.x*16 + pixL;
    int b  = pixG / HWSZ;
    int hw = pixG % HWSZ;
    {   // cooperative ref load (direct from [B][C][HW], strided): thread (pixL,c4) -> 4 ch
        int c4 = tid & 15;
        const float* rp = ref_f + (size_t)b*CC*HWSZ + (size_t)(c4*4)*HWSZ + hw;
        float f0 = rp[0];
        float f1 = rp[HWSZ];
        float f2 = rp[2*HWSZ];
        float f3 = rp[3*HWSZ];
        half2_t h0 = { (_Float16)f0, (_Float16)f1 };
        half2_t h1 = { (_Float16)f2, (_Float16)f3 };
        refU[pixL][c4*2+0] = as_u(h0);
        refU[pixL][c4*2+1] = as_u(h1);
    }
    __syncthreads();

    int h  = hw / WW;
    int w  = hw % WW;
    const float* pw = wsc + 96;
    const float* sn = wsc + 385;
    float depth = depth_sample[((size_t)b*DD + d)*HWSZ + hw];
    float xf = (float)w, yf = (float)h;

    float simsum[8];
    #pragma unroll
    for (int g=0; g<8; ++g) simsum[g] = 0.f;
    float wsum = 0.f;

    #pragma unroll
    for (int v=0; v<VV; ++v) {
        const float* pm = wsc + (v*BB + b)*12;   // wave-uniform -> s_load
        float rx = pm[0]*xf + pm[1]*yf + pm[2];
        float ry = pm[3]*xf + pm[4]*yf + pm[5];
        float rz = pm[6]*xf + pm[7]*yf + pm[8];
        float px = rx*depth + pm[9];
        float py = ry*depth + pm[10];
        float pz = rz*depth + pm[11];
        if (pz <= 0.001f) { px = (float)WW; py = (float)HH; pz = 1.f; }
        float ix = px/pz, iy = py/pz;
        float x0f = floorf(ix), y0f = floorf(iy);
        float wx1 = ix - x0f, wy1 = iy - y0f;
        float vx0 = (x0f      >= 0.f && x0f      <= (float)(WW-1)) ? 1.f : 0.f;
        float vx1 = (x0f+1.f  >= 0.f && x0f+1.f  <= (float)(WW-1)) ? 1.f : 0.f;
        float vy0 = (y0f      >= 0.f && y0f      <= (float)(HH-1)) ? 1.f : 0.f;
        float vy1 = (y0f+1.f  >= 0.f && y0f+1.f  <= (float)(HH-1)) ? 1.f : 0.f;
        float tw00 = (1.f-wx1)*(1.f-wy1)*vx0*vy0;
        float tw10 = wx1*(1.f-wy1)*vx1*vy0;
        float tw01 = (1.f-wx1)*wy1*vx0*vy1;
        float tw11 = wx1*wy1*vx1*vy1;
        int x0c = (int)fminf(fmaxf(x0f,     0.f), (float)(WW-1));
        int x1c = (int)fminf(fmaxf(x0f+1.f, 0.f), (float)(WW-1));
        int y0c = (int)fminf(fmaxf(y0f,     0.f), (float)(HH-1));
        int y1c = (int)fminf(fmaxf(y0f+1.f, 0.f), (float)(HH-1));

        const unsigned* sp  = src_u + (size_t)(v*BB + b)*HWSZ*32;   // 32 uints = 64 fp16 ch
        const unsigned* p00 = sp + (size_t)(y0c*WW + x0c)*32;
        const unsigned* p10 = sp + (size_t)(y0c*WW + x1c)*32;
        const unsigned* p01 = sp + (size_t)(y1c*WW + x0c)*32;
        const unsigned* p11 = sp + (size_t)(y1c*WW + x1c)*32;

        float sim[8];
        #pragma unroll
        for (int g=0; g<8; ++g) {
            uint4 R  = *(const uint4*)&refU[pixL][g*4];
            uint4 A  = *(const uint4*)(p00 + g*4);
            uint4 Bv = *(const uint4*)(p10 + g*4);
            uint4 Cv = *(const uint4*)(p01 + g*4);
            uint4 E  = *(const uint4*)(p11 + g*4);
            float d00 = dot8h(A,  R);
            float d10 = dot8h(Bv, R);
            float d01 = dot8h(Cv, R);
            float d11 = dot8h(E,  R);
            sim[g] = 0.125f*(tw00*d00 + tw10*d10 + tw01*d01 + tw11*d11);
        }

        float y = pixnet(pw, sim);
        float sg = 1.f/(1.f + __expf(-y));

        // max over the 16 depth lanes of this pixel
        float vw = sg;
        vw = fmaxf(vw, __shfl_xor(vw, 1));
        vw = fmaxf(vw, __shfl_xor(vw, 2));
        vw = fmaxf(vw, __shfl_xor(vw, 4));
        vw = fmaxf(vw, __shfl_xor(vw, 8));

        #pragma unroll
        for (int g=0; g<8; ++g) simsum[g] += sim[g]*vw;
        wsum += vw;
        if (d == 0) vw_out[(size_t)(b*VV + v)*HWSZ + hw] = vw;
    }

    float invw = 1.f/wsum;
    float sa[8];
    #pragma unroll
    for (int g=0; g<8; ++g) sa[g] = simsum[g]*invw;
    float s = pixnet(sn, sa);

    s_buf[(size_t)pixG*DD + d] = s;   // [B,HW,D] (D contiguous; 64B/px record)
}

// ---------------- final: grid_sample(s) + agg + softmax + depth ----------------
// block = 256 = 64 pixels x 4 j-threads; j handles nn in {j, j+4, j+8}.
__global__ __launch_bounds__(256) void eval_out_k(const float* __restrict__ s_buf,
                                                  const float* __restrict__ grid,
                                                  const float* __restrict__ weight,
                                                  const float* __restrict__ depth_sample,
                                                  const int* __restrict__ is_inverse,
                                                  float* __restrict__ out) {
    __shared__ float part[4][64][17];
    int tid = threadIdx.x;
    int px  = tid & 63;
    int j   = tid >> 6;
    int t   = blockIdx.x*64 + px;
    int b  = t / HWSZ;
    int hw = t % HWSZ;
    int h  = hw / WW;
    int w  = hw % WW;

    float agg[DD];
    #pragma unroll
    for (int d=0; d<DD; ++d) agg[d] = 0.f;

    #pragma unroll
    for (int k=0; k<3; ++k) {
        int nn = j + k*4;
        if (nn < NNB) {            // wave-uniform branch (wave = fixed j)
            const float* gp = grid + (((size_t)b*NNB*HH + nn*HH + h)*WW + w)*2;
            float gx = gp[0], gy = gp[1];
            float ix = ((gx+1.f)*WW - 1.f)*0.5f;
            float iy = ((gy+1.f)*HH - 1.f)*0.5f;
            float x0f = floorf(ix), y0f = floorf(iy);
            float wx1 = ix - x0f, wy1 = iy - y0f;
            int x0 = (int)x0f, y0 = (int)y0f;
            int x0c = x0 < 0 ? 0 : (x0 > WW-1 ? WW-1 : x0);
            int x1c = x0+1 < 0 ? 0 : (x0+1 > WW-1 ? WW-1 : x0+1);
            int y0c = y0 < 0 ? 0 : (y0 > HH-1 ? HH-1 : y0);
            int y1c = y0+1 < 0 ? 0 : (y0+1 > HH-1 ? HH-1 : y0+1);
            float w00 = (1.f-wx1)*(1.f-wy1), w10 = wx1*(1.f-wy1);
            float w01 = (1.f-wx1)*wy1,       w11 = wx1*wy1;
            const float* p00 = s_buf + ((size_t)b*HWSZ + y0c*WW + x0c)*DD;
            const float* p10 = s_buf + ((size_t)b*HWSZ + y0c*WW + x1c)*DD;
            const float* p01 = s_buf + ((size_t)b*HWSZ + y1c*WW + x0c)*DD;
            const float* p11 = s_buf + ((size_t)b*HWSZ + y1c*WW + x1c)*DD;
            const float* wp  = weight + ((size_t)b*DD*NNB + nn)*HWSZ + hw;
            #pragma unroll
            for (int q=0; q<4; ++q) {
                float4 v00 = *(const float4*)(p00 + q*4);
                float4 v10 = *(const float4*)(p10 + q*4);
                float4 v01 = *(const float4*)(p01 + q*4);
                float4 v11 = *(const float4*)(p11 + q*4);
                float s0 = w00*v00.x + w10*v10.x + w01*v01.x + w11*v11.x;
                float s1 = w00*v00.y + w10*v10.y + w01*v01.y + w11*v11.y;
                float s2 = w00*v00.z + w10*v10.z + w01*v01.z + w11*v11.z;
                float s3 = w00*v00.w + w10*v10.w + w01*v01.w + w11*v11.w;
                agg[q*4+0] += s0 * wp[(size_t)(q*4+0)*NNB*HWSZ];
                agg[q*4+1] += s1 * wp[(size_t)(q*4+1)*NNB*HWSZ];
                agg[q*4+2] += s2 * wp[(size_t)(q*4+2)*NNB*HWSZ];
                agg[q*4+3] += s3 * wp[(size_t)(q*4+3)*NNB*HWSZ];
            }
        }
    }

    #pragma unroll
    for (int d=0; d<DD; ++d) part[j][px][d] = agg[d];
    __syncthreads();
    if (j != 0) return;

    #pragma unroll
    for (int d=0; d<DD; ++d)
        agg[d] = part[0][px][d] + part[1][px][d] + part[2][px][d] + part[3][px][d];

    float m = agg[0];
    #pragma unroll
    for (int d=1; d<DD; ++d) m = fmaxf(m, agg[d]);
    float e[DD], sum = 0.f;
    #pragma unroll
    for (int d=0; d<DD; ++d) { e[d] = __expf(agg[d]-m); sum += e[d]; }
    float inv = 1.f/sum;

    const float* dsp = depth_sample + (size_t)b*DD*HWSZ + hw;
    float* sco = out + BB*HWSZ + (size_t)b*DD*HWSZ + hw;
    float dep = 0.f;
    if (*is_inverse) {
        float di = 0.f;
        #pragma unroll
        for (int d=0; d<DD; ++d) { float sc = e[d]*inv; sco[(size_t)d*HWSZ] = sc; di += (float)d*sc; }
        float invmin = 1.f/dsp[(size_t)(DD-1)*HWSZ];
        float invmax = 1.f/dsp[0];
        dep = 1.f/(invmax + di/(float)(DD-1)*(invmin-invmax));
    } else {
        #pragma unroll
        for (int d=0; d<DD; ++d) { float sc = e[d]*inv; sco[(size_t)d*HWSZ] = sc; dep += dsp[(size_t)d*HWSZ]*sc; }
    }
    out[t] = dep;   // depth [B,H,W]
}

extern "C" void kernel_launch(void* const* d_in, const int* in_sizes, int n_in,
                              void* d_out, int out_size, void* d_ws, size_t ws_size,
                              hipStream_t stream) {
    const float* ref_feature  = (const float*)d_in[0];
    const float* src_features = (const float*)d_in[1];
    const float* ref_proj     = (const float*)d_in[2];
    const float* src_projs    = (const float*)d_in[3];
    const float* depth_sample = (const float*)d_in[4];
    const float* grid         = (const float*)d_in[5];
    const float* weight       = (const float*)d_in[6];
    const float* pw_w0  = (const float*)d_in[7];
    const float* pw_g0  = (const float*)d_in[8];
    const float* pw_b0  = (const float*)d_in[9];
    const float* pw_w1  = (const float*)d_in[10];
    const float* pw_g1  = (const float*)d_in[11];
    const float* pw_b1  = (const float*)d_in[12];
    const float* pw_w2  = (const float*)d_in[13];
    const float* pw_c2b = (const float*)d_in[14];
    const float* sn_w0  = (const float*)d_in[15];
    const float* sn_g0  = (const float*)d_in[16];
    const float* sn_b0  = (const float*)d_in[17];
    const float* sn_w1  = (const float*)d_in[18];
    const float* sn_g1  = (const float*)d_in[19];
    const float* sn_b1  = (const float*)d_in[20];
    const float* sn_w2  = (const float*)d_in[21];
    const float* sn_c2b = (const float*)d_in[22];
    const int*   is_inverse = (const int*)d_in[23];
    float* out = (float*)d_out;

    float*    ws    = (float*)d_ws;
    _Float16* src_h = (_Float16*)(ws + 1024);                    // V*B*HW*64 fp16
    float*    s_buf = ws + 1024 + ((size_t)VV*BB*HWSZ*64)/2;     // B*HW*D fp32
    size_t need = (size_t)(1024 + (size_t)VV*BB*HWSZ*32 + (size_t)BB*HWSZ*DD)*sizeof(float);
    if (ws_size < need) return;  // workspace too small — cannot run

    prep_k<<<1, 128, 0, stream>>>(ref_proj, src_projs,
                                  pw_w0, pw_g0, pw_b0, pw_w1, pw_g1, pw_b1, pw_w2, pw_c2b,
                                  sn_w0, sn_g0, sn_b0, sn_w1, sn_g1, sn_b1, sn_w2, sn_c2b,
                                  ws);
    transpose_h_k<<<dim3(HWSZ/64, VV*BB), 256, 0, stream>>>(src_features, src_h);
    eval_main_k<<<(BB*HWSZ)/16, 256, 0, stream>>>(ref_feature, (const unsigned*)src_h, ws,
                                                  depth_sample, s_buf,
                                                  out + BB*HWSZ + BB*DD*HWSZ);
    eval_out_k<<<(BB*HWSZ)/64, 256, 0, stream>>>(s_buf, grid, weight, depth_sample,
                                                 is_inverse, out);
}

// Round 11
// 236.004 us; speedup vs baseline: 1.4834x; 1.0721x over previous
//
#include <hip/hip_runtime.h>
#include <math.h>

#define BB 2
#define CC 64
#define HH 128
#define WW 160
#define DD 16
#define VV 4
#define NNB 9
#define GG 8
#define HWSZ (HH*WW)
#define BNS 0.99999500003749977f  // 1/sqrt(1+1e-5)

typedef _Float16 half2_t __attribute__((ext_vector_type(2)));
typedef __fp16   fp16x2 __attribute__((ext_vector_type(2)));

__device__ inline half2_t as_h2(unsigned u){ union { unsigned u; half2_t h; } x; x.u = u; return x.h; }
__device__ inline unsigned as_u(half2_t h){ union { unsigned u; half2_t h; } x; x.h = h; return x.u; }
__device__ inline half2_t pkrtz(float a, float b){
    union { fp16x2 f; half2_t h; } x; x.f = __builtin_amdgcn_cvt_pkrtz(a, b); return x.h;
}

// fp16 8-element dot with fp32 accumulate via v_dot2_f32_f16
__device__ inline float dot8h(uint4 a, uint4 r) {
    float s = __builtin_amdgcn_fdot2(as_h2(a.x), as_h2(r.x), 0.f, false);
    s = __builtin_amdgcn_fdot2(as_h2(a.y), as_h2(r.y), s, false);
    s = __builtin_amdgcn_fdot2(as_h2(a.z), as_h2(r.z), s, false);
    s = __builtin_amdgcn_fdot2(as_h2(a.w), as_h2(r.w), s, false);
    return s;
}

// fp16-weight pixel net 8->16->8->1 (fp32 accumulate, fp32 bias/w2)
// W0: 16 rows x 4 half2-words; W1: 8 rows x 8 half2-words (wave-uniform -> s_load)
__device__ inline float pixnet_h(const unsigned* __restrict__ W0, const float* __restrict__ b0,
                                 const unsigned* __restrict__ W1, const float* __restrict__ b1,
                                 const float* __restrict__ w2, float b2, const float* sim) {
    half2_t sh[4];
    #pragma unroll
    for (int j=0;j<4;++j) sh[j] = pkrtz(sim[2*j], sim[2*j+1]);
    float h0[16];
    #pragma unroll
    for (int o=0;o<16;++o) {
        float a = b0[o];
        #pragma unroll
        for (int j=0;j<4;++j) a = __builtin_amdgcn_fdot2(sh[j], as_h2(W0[o*4+j]), a, false);
        h0[o] = fmaxf(a, 0.f);
    }
    half2_t hh[8];
    #pragma unroll
    for (int j=0;j<8;++j) hh[j] = pkrtz(h0[2*j], h0[2*j+1]);
    float acc = b2;
    #pragma unroll
    for (int o=0;o<8;++o) {
        float a = b1[o];
        #pragma unroll
        for (int j=0;j<8;++j) a = __builtin_amdgcn_fdot2(hh[j], as_h2(W1[o*8+j]), a, false);
        acc += w2[o]*fmaxf(a, 0.f);
    }
    return acc;
}

// ---------------- 4x4 inverse (adjugate) ----------------
__device__ inline void inv4(const float* m, float* o) {
    float inv[16];
    inv[0]  =  m[5]*m[10]*m[15] - m[5]*m[11]*m[14] - m[9]*m[6]*m[15] + m[9]*m[7]*m[14] + m[13]*m[6]*m[11] - m[13]*m[7]*m[10];
    inv[4]  = -m[4]*m[10]*m[15] + m[4]*m[11]*m[14] + m[8]*m[6]*m[15] - m[8]*m[7]*m[14] - m[12]*m[6]*m[11] + m[12]*m[7]*m[10];
    inv[8]  =  m[4]*m[9]*m[15]  - m[4]*m[11]*m[13] - m[8]*m[5]*m[15] + m[8]*m[7]*m[13] + m[12]*m[5]*m[11] - m[12]*m[7]*m[9];
    inv[12] = -m[4]*m[9]*m[14]  + m[4]*m[10]*m[13] + m[8]*m[5]*m[14] - m[8]*m[6]*m[13] - m[12]*m[5]*m[10] + m[12]*m[6]*m[9];
    inv[1]  = -m[1]*m[10]*m[15] + m[1]*m[11]*m[14] + m[9]*m[2]*m[15] - m[9]*m[3]*m[14] - m[13]*m[2]*m[11] + m[13]*m[3]*m[10];
    inv[5]  =  m[0]*m[10]*m[15] - m[0]*m[11]*m[14] - m[8]*m[2]*m[15] + m[8]*m[3]*m[14] + m[12]*m[2]*m[11] - m[12]*m[3]*m[10];
    inv[9]  = -m[0]*m[9]*m[15]  + m[0]*m[11]*m[13] + m[8]*m[1]*m[15] - m[8]*m[3]*m[13] - m[12]*m[1]*m[11] + m[12]*m[3]*m[9];
    inv[13] =  m[0]*m[9]*m[14]  - m[0]*m[10]*m[13] - m[8]*m[1]*m[14] + m[8]*m[2]*m[13] + m[12]*m[1]*m[10] - m[12]*m[2]*m[9];
    inv[2]  =  m[1]*m[6]*m[15]  - m[1]*m[7]*m[14]  - m[5]*m[2]*m[15] + m[5]*m[3]*m[14] + m[13]*m[2]*m[7]  - m[13]*m[3]*m[6];
    inv[6]  = -m[0]*m[6]*m[15]  + m[0]*m[7]*m[14]  + m[4]*m[2]*m[15] - m[4]*m[3]*m[14] - m[12]*m[2]*m[7]  + m[12]*m[3]*m[6];
    inv[10] =  m[0]*m[5]*m[15]  - m[0]*m[7]*m[13]  - m[4]*m[1]*m[15] + m[4]*m[3]*m[13] + m[12]*m[1]*m[7]  - m[12]*m[3]*m[5];
    inv[14] = -m[0]*m[5]*m[14]  + m[0]*m[6]*m[13]  + m[4]*m[1]*m[14] - m[4]*m[2]*m[13] - m[12]*m[1]*m[6]  + m[12]*m[2]*m[5];
    inv[3]  = -m[1]*m[6]*m[11]  + m[1]*m[7]*m[10]  + m[5]*m[2]*m[11] - m[5]*m[3]*m[10] - m[9]*m[2]*m[7]   + m[9]*m[3]*m[6];
    inv[7]  =  m[0]*m[6]*m[11]  - m[0]*m[7]*m[10]  - m[4]*m[2]*m[11] + m[4]*m[3]*m[10] + m[8]*m[2]*m[7]   - m[8]*m[3]*m[6];
    inv[11] = -m[0]*m[5]*m[11]  + m[0]*m[7]*m[9]   + m[4]*m[1]*m[11] - m[4]*m[3]*m[9]  - m[8]*m[1]*m[7]   + m[8]*m[3]*m[5];
    inv[15] =  m[0]*m[5]*m[10]  - m[0]*m[6]*m[9]   - m[4]*m[1]*m[10] + m[4]*m[2]*m[9]  + m[8]*m[1]*m[6]   - m[8]*m[2]*m[5];
    float det = m[0]*inv[0] + m[1]*inv[4] + m[2]*inv[8] + m[3]*inv[12];
    det = 1.0f/det;
    #pragma unroll
    for (int i=0;i<16;++i) o[i] = inv[i]*det;
}

// ---------------- transpose src -> fp16 [img][HW][64], with prep fused in block (0,0) ----------------
// ws layout (32-bit words): [0..95] proj (V*B x 12)
//   pw: W0h [96..159], b0 [160..175], W1h [176..239], b1 [240..247], w2 [248..255], b2 [256]
//   sn: W0h [272..335], b0 [336..351], W1h [352..415], b1 [416..423], w2 [424..431], b2 [432]
__global__ __launch_bounds__(256) void transpose_h_k(const float* __restrict__ src,
                                                     _Float16* __restrict__ dst,
                                                     const float* __restrict__ ref_proj,
                                                     const float* __restrict__ src_projs,
                                                     const float* __restrict__ pw_w0, const float* __restrict__ pw_g0, const float* __restrict__ pw_b0,
                                                     const float* __restrict__ pw_w1, const float* __restrict__ pw_g1, const float* __restrict__ pw_b1,
                                                     const float* __restrict__ pw_w2, const float* __restrict__ pw_c2b,
                                                     const float* __restrict__ sn_w0, const float* __restrict__ sn_g0, const float* __restrict__ sn_b0,
                                                     const float* __restrict__ sn_w1, const float* __restrict__ sn_g1, const float* __restrict__ sn_b1,
                                                     const float* __restrict__ sn_w2, const float* __restrict__ sn_c2b,
                                                     float* __restrict__ ws) {
    int tid = threadIdx.x;
    if (blockIdx.x == 0 && blockIdx.y == 0) {   // prep duty
        unsigned* wsu = (unsigned*)ws;
        int t = tid;
        if (t < VV*BB) {
            int b = t % BB;
            float Mi[16];
            inv4(ref_proj + b*16, Mi);
            const float* A = src_projs + t*16;
            float P[16];
            #pragma unroll
            for (int i=0;i<4;++i)
                #pragma unroll
                for (int j=0;j<4;++j) {
                    float s = 0.f;
                    #pragma unroll
                    for (int k=0;k<4;++k) s += A[i*4+k]*Mi[k*4+j];
                    P[i*4+j] = s;
                }
            float* o = ws + t*12;
            o[0]=P[0]; o[1]=P[1]; o[2]=P[2];
            o[3]=P[4]; o[4]=P[5]; o[5]=P[6];
            o[6]=P[8]; o[7]=P[9]; o[8]=P[10];
            o[9]=P[3]; o[10]=P[7]; o[11]=P[11];
        }
        if (t < 64) {
            int o0 = t>>2, j0 = t&3;
            float g0p = pw_g0[o0]*BNS;
            wsu[96+t]  = as_u(pkrtz(pw_w0[o0*8+2*j0]*g0p,   pw_w0[o0*8+2*j0+1]*g0p));
            float g0s = sn_g0[o0]*BNS;
            wsu[272+t] = as_u(pkrtz(sn_w0[o0*8+2*j0]*g0s,   sn_w0[o0*8+2*j0+1]*g0s));
            int o1 = t>>3, j1 = t&7;
            float g1p = pw_g1[o1]*BNS;
            wsu[176+t] = as_u(pkrtz(pw_w1[o1*16+2*j1]*g1p,  pw_w1[o1*16+2*j1+1]*g1p));
            float g1s = sn_g1[o1]*BNS;
            wsu[352+t] = as_u(pkrtz(sn_w1[o1*16+2*j1]*g1s,  sn_w1[o1*16+2*j1+1]*g1s));
        }
        if (t < 16) { ws[160+t]=pw_b0[t]; ws[336+t]=sn_b0[t]; }
        if (t < 8)  { ws[240+t]=pw_b1[t]; ws[248+t]=pw_w2[t];
                      ws[416+t]=sn_b1[t]; ws[424+t]=sn_w2[t]; }
        if (t == 0) { ws[256]=pw_c2b[0]; ws[432]=sn_c2b[0]; }
    }

    __shared__ float tb[64][65];
    int img = blockIdx.y;
    int n0  = blockIdx.x * 64;
    const float* ip = src + (size_t)img*64*HWSZ;
    _Float16*    op = dst + (size_t)img*HWSZ*64;
    #pragma unroll
    for (int i=0;i<4;++i) {
        int idx = i*256 + tid;
        int c  = idx >> 4;        // channel 0..63 (16 lanes share one c)
        int p4 = idx & 15;        // px-quad
        float4 v = *(const float4*)(ip + (size_t)c*HWSZ + n0 + p4*4);
        tb[c][p4*4+0]=v.x; tb[c][p4*4+1]=v.y; tb[c][p4*4+2]=v.z; tb[c][p4*4+3]=v.w;
    }
    __syncthreads();
    #pragma unroll
    for (int i=0;i<4;++i) {
        int idx = i*256 + tid;
        int n  = idx >> 4;        // px 0..63
        int cq = idx & 15;        // channel-quad
        uint2 u;
        u.x = as_u(pkrtz(tb[cq*4+0][n], tb[cq*4+1][n]));
        u.y = as_u(pkrtz(tb[cq*4+2][n], tb[cq*4+3][n]));
        *(uint2*)(op + (size_t)(n0+n)*64 + cq*4) = u;
    }
}

// ---------------- main fused kernel (fp16 gather + fp16 nets, 1 depth/thread) ----------------
// block = 256 threads = 16 pixels x 16 depths.
__global__ __launch_bounds__(256) void eval_main_k(const float* __restrict__ ref_f,
                                                   const unsigned* __restrict__ src_u,
                                                   const float* __restrict__ wsc,
                                                   const float* __restrict__ depth_sample,
                                                   float* __restrict__ s_buf,
                                                   float* __restrict__ vw_out) {
    __shared__ __align__(16) unsigned refU[16][36];   // 16 px x 64ch fp16 (32 uints, pad 36)
    int tid  = threadIdx.x;
    int pixL = tid >> 4;
    int d    = tid & 15;
    int pixG = blockIdx.x*16 + pixL;
    int b  = pixG / HWSZ;
    int hw = pixG % HWSZ;
    {   // cooperative ref load (direct from [B][C][HW], strided): thread (pixL,c4) -> 4 ch
        int c4 = tid & 15;
        const float* rp = ref_f + (size_t)b*CC*HWSZ + (size_t)(c4*4)*HWSZ + hw;
        float f0 = rp[0];
        float f1 = rp[HWSZ];
        float f2 = rp[2*HWSZ];
        float f3 = rp[3*HWSZ];
        refU[pixL][c4*2+0] = as_u(pkrtz(f0, f1));
        refU[pixL][c4*2+1] = as_u(pkrtz(f2, f3));
    }
    __syncthreads();

    int h  = hw / WW;
    int w  = hw % WW;
    const unsigned* wsu = (const unsigned*)wsc;
    float depth = depth_sample[((size_t)b*DD + d)*HWSZ + hw];
    float xf = (float)w, yf = (float)h;

    float simsum[8];
    #pragma unroll
    for (int g=0; g<8; ++g) simsum[g] = 0.f;
    float wsum = 0.f;

    #pragma unroll
    for (int v=0; v<VV; ++v) {
        const float* pm = wsc + (v*BB + b)*12;   // wave-uniform -> s_load
        float rx = pm[0]*xf + pm[1]*yf + pm[2];
        float ry = pm[3]*xf + pm[4]*yf + pm[5];
        float rz = pm[6]*xf + pm[7]*yf + pm[8];
        float px = rx*depth + pm[9];
        float py = ry*depth + pm[10];
        float pz = rz*depth + pm[11];
        if (pz <= 0.001f) { px = (float)WW; py = (float)HH; pz = 1.f; }
        float ix = px/pz, iy = py/pz;
        float x0f = floorf(ix), y0f = floorf(iy);
        float wx1 = ix - x0f, wy1 = iy - y0f;
        float vx0 = (x0f      >= 0.f && x0f      <= (float)(WW-1)) ? 1.f : 0.f;
        float vx1 = (x0f+1.f  >= 0.f && x0f+1.f  <= (float)(WW-1)) ? 1.f : 0.f;
        float vy0 = (y0f      >= 0.f && y0f      <= (float)(HH-1)) ? 1.f : 0.f;
        float vy1 = (y0f+1.f  >= 0.f && y0f+1.f  <= (float)(HH-1)) ? 1.f : 0.f;
        float tw00 = (1.f-wx1)*(1.f-wy1)*vx0*vy0;
        float tw10 = wx1*(1.f-wy1)*vx1*vy0;
        float tw01 = (1.f-wx1)*wy1*vx0*vy1;
        float tw11 = wx1*wy1*vx1*vy1;
        int x0c = (int)fminf(fmaxf(x0f,     0.f), (float)(WW-1));
        int x1c = (int)fminf(fmaxf(x0f+1.f, 0.f), (float)(WW-1));
        int y0c = (int)fminf(fmaxf(y0f,     0.f), (float)(HH-1));
        int y1c = (int)fminf(fmaxf(y0f+1.f, 0.f), (float)(HH-1));

        const unsigned* sp  = src_u + (size_t)(v*BB + b)*HWSZ*32;   // 32 uints = 64 fp16 ch
        const unsigned* p00 = sp + (size_t)(y0c*WW + x0c)*32;
        const unsigned* p10 = sp + (size_t)(y0c*WW + x1c)*32;
        const unsigned* p01 = sp + (size_t)(y1c*WW + x0c)*32;
        const unsigned* p11 = sp + (size_t)(y1c*WW + x1c)*32;

        float sim[8];
        #pragma unroll
        for (int g=0; g<8; ++g) {
            uint4 R  = *(const uint4*)&refU[pixL][g*4];
            uint4 A  = *(const uint4*)(p00 + g*4);
            uint4 Bv = *(const uint4*)(p10 + g*4);
            uint4 Cv = *(const uint4*)(p01 + g*4);
            uint4 E  = *(const uint4*)(p11 + g*4);
            float d00 = dot8h(A,  R);
            float d10 = dot8h(Bv, R);
            float d01 = dot8h(Cv, R);
            float d11 = dot8h(E,  R);
            sim[g] = 0.125f*(tw00*d00 + tw10*d10 + tw01*d01 + tw11*d11);
        }

        float y = pixnet_h(wsu+96, wsc+160, wsu+176, wsc+240, wsc+248, wsc[256], sim);
        float sg = 1.f/(1.f + __expf(-y));

        // max over the 16 depth lanes of this pixel
        float vw = sg;
        vw = fmaxf(vw, __shfl_xor(vw, 1));
        vw = fmaxf(vw, __shfl_xor(vw, 2));
        vw = fmaxf(vw, __shfl_xor(vw, 4));
        vw = fmaxf(vw, __shfl_xor(vw, 8));

        #pragma unroll
        for (int g=0; g<8; ++g) simsum[g] += sim[g]*vw;
        wsum += vw;
        if (d == 0) vw_out[(size_t)(b*VV + v)*HWSZ + hw] = vw;
    }

    float invw = 1.f/wsum;
    float sa[8];
    #pragma unroll
    for (int g=0; g<8; ++g) sa[g] = simsum[g]*invw;
    float s = pixnet_h(wsu+272, wsc+336, wsu+352, wsc+416, wsc+424, wsc[432], sa);

    s_buf[(size_t)pixG*DD + d] = s;   // [B,HW,D] (D contiguous; 64B/px record)
}

// ---------------- final: grid_sample(s) + agg + softmax + depth ----------------
// block = 256 = 64 pixels x 4 j-threads; j handles nn in {j, j+4, j+8}.
__global__ __launch_bounds__(256) void eval_out_k(const float* __restrict__ s_buf,
                                                  const float* __restrict__ grid,
                                                  const float* __restrict__ weight,
                                                  const float* __restrict__ depth_sample,
                                                  const int* __restrict__ is_inverse,
                                                  float* __restrict__ out) {
    __shared__ float part[4][64][17];
    int tid = threadIdx.x;
    int px  = tid & 63;
    int j   = tid >> 6;
    int t   = blockIdx.x*64 + px;
    int b  = t / HWSZ;
    int hw = t % HWSZ;
    int h  = hw / WW;
    int w  = hw % WW;

    float agg[DD];
    #pragma unroll
    for (int d=0; d<DD; ++d) agg[d] = 0.f;

    #pragma unroll
    for (int k=0; k<3; ++k) {
        int nn = j + k*4;
        if (nn < NNB) {            // wave-uniform branch (wave = fixed j)
            const float* gp = grid + (((size_t)b*NNB*HH + nn*HH + h)*WW + w)*2;
            float gx = gp[0], gy = gp[1];
            float ix = ((gx+1.f)*WW - 1.f)*0.5f;
            float iy = ((gy+1.f)*HH - 1.f)*0.5f;
            float x0f = floorf(ix), y0f = floorf(iy);
            float wx1 = ix - x0f, wy1 = iy - y0f;
            int x0 = (int)x0f, y0 = (int)y0f;
            int x0c = x0 < 0 ? 0 : (x0 > WW-1 ? WW-1 : x0);
            int x1c = x0+1 < 0 ? 0 : (x0+1 > WW-1 ? WW-1 : x0+1);
            int y0c = y0 < 0 ? 0 : (y0 > HH-1 ? HH-1 : y0);
            int y1c = y0+1 < 0 ? 0 : (y0+1 > HH-1 ? HH-1 : y0+1);
            float w00 = (1.f-wx1)*(1.f-wy1), w10 = wx1*(1.f-wy1);
            float w01 = (1.f-wx1)*wy1,       w11 = wx1*wy1;
            const float* p00 = s_buf + ((size_t)b*HWSZ + y0c*WW + x0c)*DD;
            const float* p10 = s_buf + ((size_t)b*HWSZ + y0c*WW + x1c)*DD;
            const float* p01 = s_buf + ((size_t)b*HWSZ + y1c*WW + x0c)*DD;
            const float* p11 = s_buf + ((size_t)b*HWSZ + y1c*WW + x1c)*DD;
            const float* wp  = weight + ((size_t)b*DD*NNB + nn)*HWSZ + hw;
            #pragma unroll
            for (int q=0; q<4; ++q) {
                float4 v00 = *(const float4*)(p00 + q*4);
                float4 v10 = *(const float4*)(p10 + q*4);
                float4 v01 = *(const float4*)(p01 + q*4);
                float4 v11 = *(const float4*)(p11 + q*4);
                float s0 = w00*v00.x + w10*v10.x + w01*v01.x + w11*v11.x;
                float s1 = w00*v00.y + w10*v10.y + w01*v01.y + w11*v11.y;
                float s2 = w00*v00.z + w10*v10.z + w01*v01.z + w11*v11.z;
                float s3 = w00*v00.w + w10*v10.w + w01*v01.w + w11*v11.w;
                agg[q*4+0] += s0 * wp[(size_t)(q*4+0)*NNB*HWSZ];
                agg[q*4+1] += s1 * wp[(size_t)(q*4+1)*NNB*HWSZ];
                agg[q*4+2] += s2 * wp[(size_t)(q*4+2)*NNB*HWSZ];
                agg[q*4+3] += s3 * wp[(size_t)(q*4+3)*NNB*HWSZ];
            }
        }
    }

    #pragma unroll
    for (int d=0; d<DD; ++d) part[j][px][d] = agg[d];
    __syncthreads();
    if (j != 0) return;

    #pragma unroll
    for (int d=0; d<DD; ++d)
        agg[d] = part[0][px][d] + part[1][px][d] + part[2][px][d] + part[3][px][d];

    float m = agg[0];
    #pragma unroll
    for (int d=1; d<DD; ++d) m = fmaxf(m, agg[d]);
    float e[DD], sum = 0.f;
    #pragma unroll
    for (int d=0; d<DD; ++d) { e[d] = __expf(agg[d]-m); sum += e[d]; }
    float inv = 1.f/sum;

    const float* dsp = depth_sample + (size_t)b*DD*HWSZ + hw;
    float* sco = out + BB*HWSZ + (size_t)b*DD*HWSZ + hw;
    float dep = 0.f;
    if (*is_inverse) {
        float di = 0.f;
        #pragma unroll
        for (int d=0; d<DD; ++d) { float sc = e[d]*inv; sco[(size_t)d*HWSZ] = sc; di += (float)d*sc; }
        float invmin = 1.f/dsp[(size_t)(DD-1)*HWSZ];
        float invmax = 1.f/dsp[0];
        dep = 1.f/(invmax + di/(float)(DD-1)*(invmin-invmax));
    } else {
        #pragma unroll
        for (int d=0; d<DD; ++d) { float sc = e[d]*inv; sco[(size_t)d*HWSZ] = sc; dep += dsp[(size_t)d*HWSZ]*sc; }
    }
    out[t] = dep;   // depth [B,H,W]
}

extern "C" void kernel_launch(void* const* d_in, const int* in_sizes, int n_in,
                              void* d_out, int out_size, void* d_ws, size_t ws_size,
                              hipStream_t stream) {
    const float* ref_feature  = (const float*)d_in[0];
    const float* src_features = (const float*)d_in[1];
    const float* ref_proj     = (const float*)d_in[2];
    const float* src_projs    = (const float*)d_in[3];
    const float* depth_sample = (const float*)d_in[4];
    const float* grid         = (const float*)d_in[5];
    const float* weight       = (const float*)d_in[6];
    const float* pw_w0  = (const float*)d_in[7];
    const float* pw_g0  = (const float*)d_in[8];
    const float* pw_b0  = (const float*)d_in[9];
    const float* pw_w1  = (const float*)d_in[10];
    const float* pw_g1  = (const float*)d_in[11];
    const float* pw_b1  = (const float*)d_in[12];
    const float* pw_w2  = (const float*)d_in[13];
    const float* pw_c2b = (const float*)d_in[14];
    const float* sn_w0  = (const float*)d_in[15];
    const float* sn_g0  = (const float*)d_in[16];
    const float* sn_b0  = (const float*)d_in[17];
    const float* sn_w1  = (const float*)d_in[18];
    const float* sn_g1  = (const float*)d_in[19];
    const float* sn_b1  = (const float*)d_in[20];
    const float* sn_w2  = (const float*)d_in[21];
    const float* sn_c2b = (const float*)d_in[22];
    const int*   is_inverse = (const int*)d_in[23];
    float* out = (float*)d_out;

    float*    ws    = (float*)d_ws;
    _Float16* src_h = (_Float16*)(ws + 1024);                    // V*B*HW*64 fp16
    float*    s_buf = ws + 1024 + ((size_t)VV*BB*HWSZ*64)/2;     // B*HW*D fp32
    size_t need = (size_t)(1024 + (size_t)VV*BB*HWSZ*32 + (size_t)BB*HWSZ*DD)*sizeof(float);
    if (ws_size < need) return;  // workspace too small — cannot run

    transpose_h_k<<<dim3(HWSZ/64, VV*BB), 256, 0, stream>>>(src_features, src_h,
                                                            ref_proj, src_projs,
                                                            pw_w0, pw_g0, pw_b0, pw_w1, pw_g1, pw_b1, pw_w2, pw_c2b,
                                                            sn_w0, sn_g0, sn_b0, sn_w1, sn_g1, sn_b1, sn_w2, sn_c2b,
                                                            ws);
    eval_main_k<<<(BB*HWSZ)/16, 256, 0, stream>>>(ref_feature, (const unsigned*)src_h, ws,
                                                  depth_sample, s_buf,
                                                  out + BB*HWSZ + BB*DD*HWSZ);
    eval_out_k<<<(BB*HWSZ)/64, 256, 0, stream>>>(s_buf, grid, weight, depth_sample,
                                                 is_inverse, out);
}